// Round 2
// baseline (34.135 us; speedup 1.0000x reference)
//
#include <hip/hip_runtime.h>

// WeightedAverage: 3x3 patch softmax-weighted average over RGB, weights from
// luminance differences, zero padding (pad taps join softmax denom with L=0).
// x: [N,3,512,512] f32, out: same.
//
// Layout: one wave (64 lanes) = one image row; each lane owns 8 consecutive
// pixels (64*8 = 512 = W). Horizontal neighbors across lane chunks come from
// __shfl_up/__shfl_down; the wave edge coincides with the image edge, so
// lane 0 / lane 63 substitute the zero-pad value directly.

#define HH 512
#define WW 512
#define HWSZ (HH * WW)

__device__ __forceinline__ float luma(float r, float g, float b) {
    return 0.2126f * r + 0.7152f * g + 0.0722f * b;
}

__global__ __launch_bounds__(256) void wavg_kernel(const float* __restrict__ x,
                                                   float* __restrict__ out) {
    const int lane = threadIdx.x & 63;
    const int wid  = threadIdx.x >> 6;
    const int row  = (blockIdx.x << 2) + wid;   // n*512 + h
    const int n    = row >> 9;
    const int h    = row & (HH - 1);
    const int w0   = lane << 3;                 // 8 px per lane

    const float* __restrict__ base = x + (size_t)n * 3 * HWSZ;

    float sw[8], sr[8], sg[8], sb[8], lc[8];
#pragma unroll
    for (int i = 0; i < 8; ++i) { sw[i] = 0.f; sr[i] = 0.f; sg[i] = 0.f; sb[i] = 0.f; }

    // Process one source row hh; taps for all 8 pixels at horizontal offsets
    // -1..+1. set_lc: this is the center row, record its luminance.
    auto do_row = [&](int hh, bool set_lc) {
        const bool inb = (unsigned)hh < HH;     // wave-uniform
        const float* Rp = base + (inb ? hh : 0) * WW + w0;
        const float4 z = make_float4(0.f, 0.f, 0.f, 0.f);
        float4 r0 = inb ? *(const float4*)(Rp)              : z;
        float4 r1 = inb ? *(const float4*)(Rp + 4)          : z;
        float4 g0 = inb ? *(const float4*)(Rp + HWSZ)       : z;
        float4 g1 = inb ? *(const float4*)(Rp + HWSZ + 4)   : z;
        float4 b0 = inb ? *(const float4*)(Rp + 2*HWSZ)     : z;
        float4 b1 = inb ? *(const float4*)(Rp + 2*HWSZ + 4) : z;

        // Extended arrays: index 0 <-> w0-1, 1..8 <-> w0..w0+7, 9 <-> w0+8.
        float rr[10], gg[10], bb[10], ll[10];
        rr[1]=r0.x; rr[2]=r0.y; rr[3]=r0.z; rr[4]=r0.w;
        rr[5]=r1.x; rr[6]=r1.y; rr[7]=r1.z; rr[8]=r1.w;
        gg[1]=g0.x; gg[2]=g0.y; gg[3]=g0.z; gg[4]=g0.w;
        gg[5]=g1.x; gg[6]=g1.y; gg[7]=g1.z; gg[8]=g1.w;
        bb[1]=b0.x; bb[2]=b0.y; bb[3]=b0.z; bb[4]=b0.w;
        bb[5]=b1.x; bb[6]=b1.y; bb[7]=b1.z; bb[8]=b1.w;

        float rL = __shfl_up(r1.w, 1);   if (lane == 0)  rL = 0.f;
        float gL = __shfl_up(g1.w, 1);   if (lane == 0)  gL = 0.f;
        float bL = __shfl_up(b1.w, 1);   if (lane == 0)  bL = 0.f;
        float rR = __shfl_down(r0.x, 1); if (lane == 63) rR = 0.f;
        float gR = __shfl_down(g0.x, 1); if (lane == 63) gR = 0.f;
        float bR = __shfl_down(b0.x, 1); if (lane == 63) bR = 0.f;
        rr[0] = rL; gg[0] = gL; bb[0] = bL;
        rr[9] = rR; gg[9] = gR; bb[9] = bR;

#pragma unroll
        for (int t = 0; t < 10; ++t) ll[t] = luma(rr[t], gg[t], bb[t]);

        if (set_lc) {
#pragma unroll
            for (int i = 0; i < 8; ++i) lc[i] = ll[i + 1];
        }

#pragma unroll
        for (int i = 0; i < 8; ++i) {
#pragma unroll
            for (int t = i; t < i + 3; ++t) {
                float d  = ll[t] - lc[i];
                float wt = __expf(-d * d);      // exponent in [-1, 0]
                sw[i] += wt;
                sr[i] += wt * rr[t];
                sg[i] += wt * gg[t];
                sb[i] += wt * bb[t];
            }
        }
    };

    do_row(h, true);        // center first (establishes lc)
    do_row(h - 1, false);
    do_row(h + 1, false);

    float inv[8];
#pragma unroll
    for (int i = 0; i < 8; ++i) inv[i] = __builtin_amdgcn_rcpf(sw[i]);  // sw in [1,9]

    float* Op = out + (size_t)n * 3 * HWSZ + h * WW + w0;
    float4 o0, o1;
    o0.x = sr[0]*inv[0]; o0.y = sr[1]*inv[1]; o0.z = sr[2]*inv[2]; o0.w = sr[3]*inv[3];
    o1.x = sr[4]*inv[4]; o1.y = sr[5]*inv[5]; o1.z = sr[6]*inv[6]; o1.w = sr[7]*inv[7];
    *(float4*)(Op)     = o0;
    *(float4*)(Op + 4) = o1;
    o0.x = sg[0]*inv[0]; o0.y = sg[1]*inv[1]; o0.z = sg[2]*inv[2]; o0.w = sg[3]*inv[3];
    o1.x = sg[4]*inv[4]; o1.y = sg[5]*inv[5]; o1.z = sg[6]*inv[6]; o1.w = sg[7]*inv[7];
    *(float4*)(Op + HWSZ)     = o0;
    *(float4*)(Op + HWSZ + 4) = o1;
    o0.x = sb[0]*inv[0]; o0.y = sb[1]*inv[1]; o0.z = sb[2]*inv[2]; o0.w = sb[3]*inv[3];
    o1.x = sb[4]*inv[4]; o1.y = sb[5]*inv[5]; o1.z = sb[6]*inv[6]; o1.w = sb[7]*inv[7];
    *(float4*)(Op + 2*HWSZ)     = o0;
    *(float4*)(Op + 2*HWSZ + 4) = o1;
}

extern "C" void kernel_launch(void* const* d_in, const int* in_sizes, int n_in,
                              void* d_out, int out_size, void* d_ws, size_t ws_size,
                              hipStream_t stream) {
    const float* x = (const float*)d_in[0];
    float* out = (float*)d_out;
    int nimg   = in_sizes[0] / (3 * HWSZ);   // 8
    int rows   = nimg * HH;                  // 4096 waves
    int blocks = rows / 4;                   // 4 waves per block
    wavg_kernel<<<blocks, 256, 0, stream>>>(x, out);
}

// Round 4
// 20.608 us; speedup vs baseline: 1.6564x; 1.6564x over previous
//
#include <hip/hip_runtime.h>

// WeightedAverage: 3x3 patch softmax-weighted average over RGB, weights from
// luminance differences, zero padding (pad taps join softmax denom with L=0,
// contribute 0 to numerator). x: [N,3,512,512] f32, out: same.
//
// R4 = R3 with native ext_vector float4 (HIP's float4 class is rejected by
// __builtin_nontemporal_store). Design: 4 px per thread, all loads clamped
// in-bounds + mask-multiplied zero-pad -> unconditional, hoistable into one
// burst. Edge taps are scalar loads on L1-resident lines. No shuffles.

#define HH 512
#define WW 512
#define HWSZ (HH * WW)

typedef float f32x4 __attribute__((ext_vector_type(4)));

__device__ __forceinline__ float luma(float r, float g, float b) {
    return 0.2126f * r + 0.7152f * g + 0.0722f * b;
}

// Load one channel-row window [w0-1 .. w0+4] into o[6], applying pad masks.
__device__ __forceinline__ void load6(const float* __restrict__ p, int w0,
                                      int wlC, int wrC, float m, float mL,
                                      float mR, float o[6]) {
    f32x4 v  = *(const f32x4*)(p + w0);
    float lv = p[wlC];
    float rv = p[wrC];
    o[0] = lv * mL;
    o[1] = v.x * m; o[2] = v.y * m; o[3] = v.z * m; o[4] = v.w * m;
    o[5] = rv * mR;
}

__device__ __forceinline__ void accum(const float rr[6], const float gg[6],
                                      const float bb[6], const float lc[4],
                                      float sw[4], float sr[4], float sg[4],
                                      float sb[4]) {
    float ll[6];
#pragma unroll
    for (int t = 0; t < 6; ++t) ll[t] = luma(rr[t], gg[t], bb[t]);
#pragma unroll
    for (int i = 0; i < 4; ++i) {
#pragma unroll
        for (int t = i; t < i + 3; ++t) {
            float d  = ll[t] - lc[i];
            float wt = __expf(-d * d);          // exponent in [-1, 0]
            sw[i] += wt;
            sr[i] += wt * rr[t];
            sg[i] += wt * gg[t];
            sb[i] += wt * bb[t];
        }
    }
}

__global__ __launch_bounds__(256) void wavg_kernel(const float* __restrict__ x,
                                                   float* __restrict__ out) {
    const int gid = blockIdx.x * 256 + threadIdx.x;   // over N*H*(W/4)
    const int w0  = (gid & 127) << 2;                 // 0..508 step 4
    const int row = gid >> 7;                         // n*512 + h
    const int n   = row >> 9;
    const int h   = row & (HH - 1);

    const float* __restrict__ base = x + (size_t)n * 3 * HWSZ;

    const int   wlC = (w0 > 0) ? w0 - 1 : 0;
    const int   wrC = (w0 + 4 < WW) ? w0 + 4 : WW - 1;
    const float mkL = (w0 > 0) ? 1.f : 0.f;
    const float mkR = (w0 + 4 < WW) ? 1.f : 0.f;

    const int   hmC = (h > 0) ? h - 1 : 0;
    const int   hpC = (h < HH - 1) ? h + 1 : HH - 1;
    const float mM  = (h > 0) ? 1.f : 0.f;
    const float mP  = (h < HH - 1) ? 1.f : 0.f;

    // ---- load burst: 27 independent, always-in-bounds loads ----
    float rc[6], gc[6], bc[6];          // center row
    float rm[6], gm[6], bm[6];          // row h-1
    float rp[6], gp[6], bp[6];          // row h+1
    load6(base + 0 * HWSZ + h * WW,   w0, wlC, wrC, 1.f, mkL,      mkR,      rc);
    load6(base + 1 * HWSZ + h * WW,   w0, wlC, wrC, 1.f, mkL,      mkR,      gc);
    load6(base + 2 * HWSZ + h * WW,   w0, wlC, wrC, 1.f, mkL,      mkR,      bc);
    load6(base + 0 * HWSZ + hmC * WW, w0, wlC, wrC, mM,  mM * mkL, mM * mkR, rm);
    load6(base + 1 * HWSZ + hmC * WW, w0, wlC, wrC, mM,  mM * mkL, mM * mkR, gm);
    load6(base + 2 * HWSZ + hmC * WW, w0, wlC, wrC, mM,  mM * mkL, mM * mkR, bm);
    load6(base + 0 * HWSZ + hpC * WW, w0, wlC, wrC, mP,  mP * mkL, mP * mkR, rp);
    load6(base + 1 * HWSZ + hpC * WW, w0, wlC, wrC, mP,  mP * mkL, mP * mkR, gp);
    load6(base + 2 * HWSZ + hpC * WW, w0, wlC, wrC, mP,  mP * mkL, mP * mkR, bp);

    // ---- compute ----
    float lc[4];
    {
        float llc[6];
#pragma unroll
        for (int t = 0; t < 6; ++t) llc[t] = luma(rc[t], gc[t], bc[t]);
#pragma unroll
        for (int i = 0; i < 4; ++i) lc[i] = llc[i + 1];
    }

    float sw[4], sr[4], sg[4], sb[4];
#pragma unroll
    for (int i = 0; i < 4; ++i) { sw[i] = 0.f; sr[i] = 0.f; sg[i] = 0.f; sb[i] = 0.f; }

    accum(rc, gc, bc, lc, sw, sr, sg, sb);
    accum(rm, gm, bm, lc, sw, sr, sg, sb);
    accum(rp, gp, bp, lc, sw, sr, sg, sb);

    float inv[4];
#pragma unroll
    for (int i = 0; i < 4; ++i) inv[i] = __builtin_amdgcn_rcpf(sw[i]);  // sw in [1,9]

    float* Op = out + (size_t)n * 3 * HWSZ + h * WW + w0;
    f32x4 o;
    o.x = sr[0]*inv[0]; o.y = sr[1]*inv[1]; o.z = sr[2]*inv[2]; o.w = sr[3]*inv[3];
    __builtin_nontemporal_store(o, (f32x4*)(Op));
    o.x = sg[0]*inv[0]; o.y = sg[1]*inv[1]; o.z = sg[2]*inv[2]; o.w = sg[3]*inv[3];
    __builtin_nontemporal_store(o, (f32x4*)(Op + HWSZ));
    o.x = sb[0]*inv[0]; o.y = sb[1]*inv[1]; o.z = sb[2]*inv[2]; o.w = sb[3]*inv[3];
    __builtin_nontemporal_store(o, (f32x4*)(Op + 2 * HWSZ));
}

extern "C" void kernel_launch(void* const* d_in, const int* in_sizes, int n_in,
                              void* d_out, int out_size, void* d_ws, size_t ws_size,
                              hipStream_t stream) {
    const float* x = (const float*)d_in[0];
    float* out = (float*)d_out;
    int total  = in_sizes[0] / (3 * 4);     // N*H*W/4 threads
    int blocks = (total + 255) / 256;       // 2048
    wavg_kernel<<<blocks, 256, 0, stream>>>(x, out);
}